// Round 1
// 1384.315 us; speedup vs baseline: 1.1699x; 1.1699x over previous
//
#include <hip/hip_runtime.h>

// ---------------------------------------------------------------------------
// MultichannelMultiheadAttention2: full decomposition
//   B=2 C=16 AM=4 HEADS=8 F=1024 W=1024 HD=128
// Pipeline:
//  1) cast_wpw: wq/wk/wv/wo_pw fp32 -> bf16
//  2) conv_qkv: 3x3 conv (x -> yq,yk,yv), written TRANSPOSED [b][am][w][f] bf16
//  3) gemm_pw<1> (q,k): C[f,w] = wpw[f,h]*y[h,w], epilogue fuses rotary and
//     stores per-head transposed Qt/Kt[b][am][head][qpos][d] bf16
//     gemm_pw<0> (v): natural store Vnat[b][am][f][w] bf16
//  4) attn_fused: flash-style fused S = QK^T/32 + prev + mask (fp32 -> qk out,
//     coalesced float4 via LDS bounce), online softmax, PV accumulate;
//     stores AT[b][am][qpos][head*128+d] bf16.  Replaces the old
//     gemm_s + softmax_stats + gemm_pv (eliminates 536 MB of S re-reads).
//  5) mix_dw: 4x4 channel mix -> a2T[b][o][w][h] bf16
//  6) gemm_pw<0> (o): wo_pw * a2 -> a3[b][am][f][w] bf16
//  7) conv_out: 3x3 conv over concat(x, a3) -> d_out(out) fp32
// ---------------------------------------------------------------------------

typedef unsigned short u16;
typedef __attribute__((ext_vector_type(8))) short bf16x8;
typedef __attribute__((ext_vector_type(4))) float f32x4;

constexpr size_t EL = 1024ull * 1024ull;  // one 1024x1024 plane

__device__ __forceinline__ u16 f2bf(float f) {
  union { float f; unsigned u; } v; v.f = f;
  return (u16)((v.u + 0x7fffu + ((v.u >> 16) & 1u)) >> 16);
}
__device__ __forceinline__ float bf2f(u16 h) {
  union { unsigned u; float f; } v; v.u = ((unsigned)h) << 16;
  return v.f;
}

// ---------------------------------------------------------------- cast weights
__global__ __launch_bounds__(256) void cast_wpw(const float* __restrict__ q,
                                                const float* __restrict__ k,
                                                const float* __restrict__ v,
                                                const float* __restrict__ o,
                                                u16* __restrict__ dst) {
  size_t i = (size_t)blockIdx.x * 256 + threadIdx.x;  // 16,777,216 total
  int mat = (int)(i >> 22);
  size_t off = i & 4194303ull;
  const float* s = (mat == 0) ? q : (mat == 1) ? k : (mat == 2) ? v : o;
  dst[i] = f2bf(s[off]);
}

// ------------------------------------------------------------------- conv qkv
// yT*[b][am][w][f]  (transposed so the pw GEMM's B^T operand is K-contiguous)
__global__ __launch_bounds__(256) void conv_qkv(
    const float* __restrict__ x, const float* __restrict__ wq,
    const float* __restrict__ bq, const float* __restrict__ wk,
    const float* __restrict__ bk, const float* __restrict__ wv,
    const float* __restrict__ bv, u16* __restrict__ yTq,
    u16* __restrict__ yTk, u16* __restrict__ yTv) {
  __shared__ float xt[18 * 18];
  const int b = blockIdx.z;
  const int f0 = blockIdx.y * 16, w0 = blockIdx.x * 16;
  const int tx = threadIdx.x & 15;   // f-local
  const int ty = threadIdx.x >> 4;   // w-local
  float acc[12];
#pragma unroll
  for (int p = 0; p < 12; ++p) acc[p] = 0.f;
  for (int c = 0; c < 16; ++c) {
    __syncthreads();
    const float* xc = x + ((size_t)(b * 16 + c) << 20);
    for (int idx = threadIdx.x; idx < 324; idx += 256) {
      int r = idx / 18, cc = idx - r * 18;
      int gf = f0 - 1 + r, gw = w0 - 1 + cc;
      float val = 0.f;
      if ((unsigned)gf < 1024u && (unsigned)gw < 1024u)
        val = xc[((size_t)gf << 10) + gw];
      xt[idx] = val;
    }
    __syncthreads();
    float xv[9];
#pragma unroll
    for (int ky = 0; ky < 3; ++ky)
#pragma unroll
      for (int kx = 0; kx < 3; ++kx)
        xv[ky * 3 + kx] = xt[(tx + ky) * 18 + (ty + kx)];
#pragma unroll
    for (int m = 0; m < 4; ++m) {
      const float* wqc = wq + (m * 16 + c) * 9;
      const float* wkc = wk + (m * 16 + c) * 9;
      const float* wvc = wv + (m * 16 + c) * 9;
#pragma unroll
      for (int t = 0; t < 9; ++t) {
        acc[m]     += xv[t] * wqc[t];
        acc[4 + m] += xv[t] * wkc[t];
        acc[8 + m] += xv[t] * wvc[t];
      }
    }
  }
  const int w = w0 + ty, f = f0 + tx;
#pragma unroll
  for (int m = 0; m < 4; ++m) {
    size_t o = ((((size_t)(b * 4 + m) << 10) + w) << 10) + f;
    yTq[o] = f2bf(acc[m] + bq[m]);
    yTk[o] = f2bf(acc[4 + m] + bk[m]);
    yTv[o] = f2bf(acc[8 + m] + bv[m]);
  }
}

// --------------------------------------------------------------- pw GEMM core
// C[f,w] = sum_h A[f,h] * Bt[w,h]; M=N=K=1024, lda=ldb=1024
// MODE 0: natural bf16 store C[z][f][w]
// MODE 1: rotary + per-head transposed store Qt[z][head][qpos][d]
template <int MODE>
__global__ __launch_bounds__(256) void gemm_pw(const u16* __restrict__ Aall,
                                               const u16* __restrict__ Ball,
                                               u16* __restrict__ Call) {
  const int z = blockIdx.z;         // b*4+am
  const int am = z & 3;
  const u16* __restrict__ A = Aall + (size_t)am * EL;   // weights per am
  const u16* __restrict__ Bt = Ball + (size_t)z * EL;
  const int bm = blockIdx.y * 128;
  const int bn = blockIdx.x * 128;
  __shared__ u16 As[128 * 40];      // padded stride 40 (bank spread)
  __shared__ u16 Bs[128 * 40];
  const int tid = threadIdx.x;
  const int lane = tid & 63, wv = tid >> 6;
  const int wm = (wv >> 1) * 64, wn = (wv & 1) * 64;
  const int mrow = lane & 15, quad = lane >> 4;
  const f32x4 fz = {0.f, 0.f, 0.f, 0.f};
  f32x4 acc[4][4];
#pragma unroll
  for (int i = 0; i < 4; ++i)
#pragma unroll
    for (int j = 0; j < 4; ++j) acc[i][j] = fz;

  for (int k0 = 0; k0 < 1024; k0 += 32) {
#pragma unroll
    for (int i = 0; i < 2; ++i) {
      const int cc = tid + i * 256;         // 0..511
      const int row = cc >> 2;              // 0..127
      const int kb = (cc & 3) * 8;          // bf16 elems within 32-wide row
      *(uint4*)(As + row * 40 + kb) =
          *(const uint4*)(A + (size_t)(bm + row) * 1024 + (k0 + kb));
      *(uint4*)(Bs + row * 40 + kb) =
          *(const uint4*)(Bt + (size_t)(bn + row) * 1024 + (k0 + kb));
    }
    __syncthreads();
    bf16x8 af[4], bfv[4];
#pragma unroll
    for (int t = 0; t < 4; ++t) {
      af[t]  = *(const bf16x8*)(As + (wm + 16 * t + mrow) * 40 + quad * 8);
      bfv[t] = *(const bf16x8*)(Bs + (wn + 16 * t + mrow) * 40 + quad * 8);
    }
#pragma unroll
    for (int mt = 0; mt < 4; ++mt)
#pragma unroll
      for (int nt = 0; nt < 4; ++nt)
        acc[mt][nt] = __builtin_amdgcn_mfma_f32_16x16x32_bf16(
            af[mt], bfv[nt], acc[mt][nt], 0, 0, 0);
    __syncthreads();
  }

  if (MODE == 0) {
    u16* C = Call + (size_t)z * EL;
#pragma unroll
    for (int mt = 0; mt < 4; ++mt) {
      const int rowb = bm + wm + 16 * mt + quad * 4;
#pragma unroll
      for (int nt = 0; nt < 4; ++nt) {
        const int col = bn + wn + 16 * nt + mrow;
#pragma unroll
        for (int r = 0; r < 4; ++r)
          C[(size_t)(rowb + r) * 1024 + col] = f2bf(acc[mt][nt][r]);
      }
    }
  } else {
    // rotary (lucidrains interleaved) + transposed per-head store
    u16* C = Call + (size_t)z * EL;   // [head][qpos][128]
    const int head = blockIdx.y;      // 128 rows == one head
#pragma unroll
    for (int mt = 0; mt < 4; ++mt) {
      const int d0 = wm + 16 * mt + quad * 4;  // within-head dim, even
      const float i1 = (float)(d0 >> 1);
      const float inv1 = __powf(10000.f, -i1 * (1.f / 64.f));
      const float inv2 = __powf(10000.f, -(i1 + 1.f) * (1.f / 64.f));
#pragma unroll
      for (int nt = 0; nt < 4; ++nt) {
        const int w = bn + wn + 16 * nt + mrow;  // qpos
        float s1, c1, s2, c2;
        __sincosf((float)w * inv1, &s1, &c1);
        __sincosf((float)w * inv2, &s2, &c2);
        const float x0 = acc[mt][nt][0], x1 = acc[mt][nt][1];
        const float x2 = acc[mt][nt][2], x3 = acc[mt][nt][3];
        ushort4 o4;
        o4.x = f2bf(x0 * c1 - x1 * s1);
        o4.y = f2bf(x1 * c1 + x0 * s1);
        o4.z = f2bf(x2 * c2 - x3 * s2);
        o4.w = f2bf(x3 * c2 + x2 * s2);
        *(ushort4*)(C + ((size_t)head * 1024 + w) * 128 + d0) = o4;
      }
    }
  }
}

// ------------------------------------------------------- fused flash attention
// One block per (z = bam*8+head, 128-row q block). 4 waves, wave w owns q rows
// [32w, 32w+32). Loop over 16 k-tiles of 64:
//   stage K/V tile -> S via MFMA -> scatter S to LDS (Sx, overlays dead K) ->
//   Phase B (coalesced): float4 prev/mask loads + fp32 S store (qk output),
//   online row max/sum, P=exp(S-m) bf16 into Ps, sf into sfl ->
//   rescale O by sf -> PV MFMA accumulate.
// Final: O /= l, store AT.
__global__ __launch_bounds__(256, 2) void attn_fused(
    const u16* __restrict__ Qt, const u16* __restrict__ Kt,
    const u16* __restrict__ Vn, const float* __restrict__ prev,
    const float* __restrict__ maskp, float* __restrict__ Sout,
    u16* __restrict__ AT) {
  const int z = blockIdx.y;
  const int bam = z >> 3, head = z & 7;
  const int bm = blockIdx.x * 128;
  const u16* __restrict__ Q = Qt + (size_t)z * (EL / 8);   // [1024 q][128 d]
  const u16* __restrict__ K = Kt + (size_t)z * (EL / 8);   // [1024 k][128 d]
  const u16* __restrict__ V =
      Vn + (size_t)bam * EL + (size_t)head * 128 * 1024;   // [128 d][1024 k]
  const float* __restrict__ Pz = prev + (size_t)z * EL;
  float* __restrict__ Sg = Sout + (size_t)z * EL;

  // LDS: Vs 18432 | Ps 18432 | sfl 512 | Sx(34816) union Ks(17408) = 72192 B
  __shared__ __align__(16) char smem[72192];
  u16* Vs = (u16*)smem;                  // [128 d][72]
  u16* Ps = (u16*)(smem + 18432);        // [128 q][72]
  float* sfl = (float*)(smem + 36864);   // [128]
  float* Sx = (float*)(smem + 37376);    // [128 q][68] fp32
  u16* Ks = (u16*)(smem + 37376);        // [64 k][136]  (overlay)

  const int tid = threadIdx.x;
  const int lane = tid & 63, wv = tid >> 6;
  const int mrow = lane & 15, quad = lane >> 4;
  const int wrow = wv * 32;              // wave's q-row base (tile-local)
  const int prow = lane >> 4;            // Phase-B row-within-group 0..3
  const int pcol4 = (lane & 15) * 4;     // Phase-B col base 0..60

  // Q fragments held in registers for the whole kernel
  bf16x8 qf[2][4];
#pragma unroll
  for (int mt = 0; mt < 2; ++mt)
#pragma unroll
    for (int kk = 0; kk < 4; ++kk)
      qf[mt][kk] = *(const bf16x8*)(
          Q + (size_t)(bm + wrow + 16 * mt + mrow) * 128 + kk * 32 + quad * 8);

  const f32x4 fz = {0.f, 0.f, 0.f, 0.f};
  f32x4 oacc[2][8];
#pragma unroll
  for (int mt = 0; mt < 2; ++mt)
#pragma unroll
    for (int nt = 0; nt < 8; ++nt) oacc[mt][nt] = fz;
  float m_st[8], l_st[8];
#pragma unroll
  for (int c = 0; c < 8; ++c) { m_st[c] = -3.0e38f; l_st[c] = 0.f; }

  for (int t = 0; t < 16; ++t) {
    const int kb = t * 64;
    // ---- stage K tile [64 k][128 d] and V tile [128 d][64 k]
#pragma unroll
    for (int i = 0; i < 4; ++i) {
      const int c = tid + i * 256;            // 0..1023
      const int row = c >> 4, c8 = (c & 15) * 8;
      *(uint4*)(Ks + row * 136 + c8) =
          *(const uint4*)(K + (size_t)(kb + row) * 128 + c8);
    }
#pragma unroll
    for (int i = 0; i < 4; ++i) {
      const int c = tid + i * 256;
      const int row = c >> 3, c8 = (c & 7) * 8;
      *(uint4*)(Vs + row * 72 + c8) =
          *(const uint4*)(V + (size_t)row * 1024 + kb + c8);
    }
    __syncthreads();

    // ---- S = Q K^T (raw, unscaled)
    f32x4 sacc[2][4];
#pragma unroll
    for (int mt = 0; mt < 2; ++mt)
#pragma unroll
      for (int nt = 0; nt < 4; ++nt) sacc[mt][nt] = fz;
#pragma unroll
    for (int kk = 0; kk < 4; ++kk) {
      bf16x8 bk[4];
#pragma unroll
      for (int nt = 0; nt < 4; ++nt)
        bk[nt] = *(const bf16x8*)(Ks + (16 * nt + mrow) * 136 + kk * 32 +
                                  quad * 8);
#pragma unroll
      for (int mt = 0; mt < 2; ++mt)
#pragma unroll
        for (int nt = 0; nt < 4; ++nt)
          sacc[mt][nt] = __builtin_amdgcn_mfma_f32_16x16x32_bf16(
              qf[mt][kk], bk[nt], sacc[mt][nt], 0, 0, 0);
    }
    __syncthreads();   // all waves done reading Ks (Sx overlays it)

    // ---- scatter S into Sx (wave-local rows; 2-way banks = free)
#pragma unroll
    for (int mt = 0; mt < 2; ++mt)
#pragma unroll
      for (int nt = 0; nt < 4; ++nt)
#pragma unroll
        for (int r = 0; r < 4; ++r)
          Sx[(wrow + 16 * mt + quad * 4 + r) * 68 + 16 * nt + mrow] =
              sacc[mt][nt][r];

    // ---- Phase B: coalesced epilogue + online softmax (wave-local rows)
#pragma unroll
    for (int c = 0; c < 8; ++c) {
      const int rloc = wrow + c * 4 + prow;                   // 0..127
      const size_t gidx = (size_t)(bm + rloc) * 1024 + kb + pcol4;
      f32x4 sx = *(const f32x4*)(Sx + rloc * 68 + pcol4);
      f32x4 pv = __builtin_nontemporal_load((const f32x4*)(Pz + gidx));
      f32x4 mv = *(const f32x4*)(maskp + gidx);
      f32x4 s;
      s.x = sx.x * 0.03125f + pv.x + mv.x;
      s.y = sx.y * 0.03125f + pv.y + mv.y;
      s.z = sx.z * 0.03125f + pv.z + mv.z;
      s.w = sx.w * 0.03125f + pv.w + mv.w;
      __builtin_nontemporal_store(s, (f32x4*)(Sg + gidx));
      float mx = fmaxf(fmaxf(s.x, s.y), fmaxf(s.z, s.w));
      mx = fmaxf(mx, __shfl_xor(mx, 1, 64));
      mx = fmaxf(mx, __shfl_xor(mx, 2, 64));
      mx = fmaxf(mx, __shfl_xor(mx, 4, 64));
      mx = fmaxf(mx, __shfl_xor(mx, 8, 64));
      const float mn = fmaxf(m_st[c], mx);
      const float sf = __expf(m_st[c] - mn);
      m_st[c] = mn;
      const float p0 = __expf(s.x - mn), p1 = __expf(s.y - mn);
      const float p2 = __expf(s.z - mn), p3 = __expf(s.w - mn);
      float rs = p0 + p1 + p2 + p3;
      rs += __shfl_xor(rs, 1, 64);
      rs += __shfl_xor(rs, 2, 64);
      rs += __shfl_xor(rs, 4, 64);
      rs += __shfl_xor(rs, 8, 64);
      l_st[c] = l_st[c] * sf + rs;
      uint2 pk;
      pk.x = (unsigned)f2bf(p0) | ((unsigned)f2bf(p1) << 16);
      pk.y = (unsigned)f2bf(p2) | ((unsigned)f2bf(p3) << 16);
      *(uint2*)(Ps + rloc * 72 + pcol4) = pk;
      if ((lane & 15) == 0) sfl[rloc] = sf;
    }

    // ---- rescale O by this tile's sf (rows wave-local; broadcast LDS reads)
#pragma unroll
    for (int mt = 0; mt < 2; ++mt)
#pragma unroll
      for (int r = 0; r < 4; ++r) {
        const float sfv = sfl[wrow + 16 * mt + quad * 4 + r];
#pragma unroll
        for (int nt = 0; nt < 8; ++nt) oacc[mt][nt][r] *= sfv;
      }

    // ---- PV: O += P * V
#pragma unroll
    for (int kk = 0; kk < 2; ++kk) {
      bf16x8 pa[2], bv[8];
#pragma unroll
      for (int mt = 0; mt < 2; ++mt)
        pa[mt] = *(const bf16x8*)(Ps + (wrow + 16 * mt + mrow) * 72 + kk * 32 +
                                  quad * 8);
#pragma unroll
      for (int nt = 0; nt < 8; ++nt)
        bv[nt] = *(const bf16x8*)(Vs + (16 * nt + mrow) * 72 + kk * 32 +
                                  quad * 8);
#pragma unroll
      for (int mt = 0; mt < 2; ++mt)
#pragma unroll
        for (int nt = 0; nt < 8; ++nt)
          oacc[mt][nt] = __builtin_amdgcn_mfma_f32_16x16x32_bf16(
              pa[mt], bv[nt], oacc[mt][nt], 0, 0, 0);
    }
    __syncthreads();   // Vs/Ks region free for next tile's staging
  }

  // ---- final normalize + store AT[bam][qpos][head*128 + d]
#pragma unroll
  for (int c = 0; c < 8; ++c)
    if ((lane & 15) == 0) sfl[wrow + c * 4 + prow] = 1.f / l_st[c];
  __syncthreads();
  u16* C = AT + (size_t)bam * EL + (size_t)head * 128;
#pragma unroll
  for (int mt = 0; mt < 2; ++mt)
#pragma unroll
    for (int r = 0; r < 4; ++r) {
      const int rloc = wrow + 16 * mt + quad * 4 + r;
      const float inv = sfl[rloc];
      const int grow = bm + rloc;
#pragma unroll
      for (int nt = 0; nt < 8; ++nt)
        C[(size_t)grow * 1024 + 16 * nt + mrow] =
            f2bf(oacc[mt][nt][r] * inv);
    }
}

// -------------------------------------------------------------- wo_dw 4x4 mix
__global__ __launch_bounds__(256) void mix_dw(const u16* __restrict__ AT,
                                              const float* __restrict__ dw,
                                              u16* __restrict__ a2T) {
  const size_t i = (size_t)blockIdx.x * 256 + threadIdx.x;  // 524288 total
  const int b = (int)(i >> 18);
  const size_t pos = (i & 262143ull) << 2;  // 4 consecutive f
  const u16* bb = AT + (size_t)b * 4 * EL + pos;
  float4 v[4];
#pragma unroll
  for (int c = 0; c < 4; ++c) {
    ushort4 t = *(const ushort4*)(bb + (size_t)c * EL);
    v[c].x = bf2f(t.x); v[c].y = bf2f(t.y); v[c].z = bf2f(t.z); v[c].w = bf2f(t.w);
  }
#pragma unroll
  for (int o = 0; o < 4; ++o) {
    const float w0 = dw[o * 4 + 0], w1 = dw[o * 4 + 1];
    const float w2 = dw[o * 4 + 2], w3 = dw[o * 4 + 3];
    ushort4 s;
    s.x = f2bf(w0 * v[0].x + w1 * v[1].x + w2 * v[2].x + w3 * v[3].x);
    s.y = f2bf(w0 * v[0].y + w1 * v[1].y + w2 * v[2].y + w3 * v[3].y);
    s.z = f2bf(w0 * v[0].z + w1 * v[1].z + w2 * v[2].z + w3 * v[3].z);
    s.w = f2bf(w0 * v[0].w + w1 * v[1].w + w2 * v[2].w + w3 * v[3].w);
    *(ushort4*)(a2T + (size_t)b * 4 * EL + (size_t)o * EL + pos) = s;
  }
}

// ------------------------------------------------------------------ conv out
__global__ __launch_bounds__(256) void conv_out(const float* __restrict__ x,
                                                const u16* __restrict__ a3,
                                                const float* __restrict__ wo,
                                                const float* __restrict__ bo,
                                                float* __restrict__ out) {
  __shared__ float xt[18 * 18];
  const int b = blockIdx.z;
  const int f0 = blockIdx.y * 16, w0 = blockIdx.x * 16;
  const int tx = threadIdx.x & 15;   // w-local
  const int ty = threadIdx.x >> 4;   // f-local
  float acc[16];
#pragma unroll
  for (int o = 0; o < 16; ++o) acc[o] = bo[o];
  for (int c = 0; c < 20; ++c) {
    __syncthreads();
    for (int idx = threadIdx.x; idx < 324; idx += 256) {
      int r = idx / 18, cc = idx - r * 18;
      int gf = f0 - 1 + r, gw = w0 - 1 + cc;
      float val = 0.f;
      if ((unsigned)gf < 1024u && (unsigned)gw < 1024u) {
        if (c < 16)
          val = x[(((size_t)(b * 16 + c) << 10) + gf) * 1024 + gw];
        else
          val = bf2f(a3[(((size_t)(b * 4 + (c - 16)) << 10) + gf) * 1024 + gw]);
      }
      xt[idx] = val;
    }
    __syncthreads();
    float xv[9];
#pragma unroll
    for (int ky = 0; ky < 3; ++ky)
#pragma unroll
      for (int kx = 0; kx < 3; ++kx)
        xv[ky * 3 + kx] = xt[(ty + ky) * 18 + (tx + kx)];
#pragma unroll
    for (int o = 0; o < 16; ++o) {
      const float* wc = wo + (o * 20 + c) * 9;
#pragma unroll
      for (int t = 0; t < 9; ++t) acc[o] += xv[t] * wc[t];
    }
  }
  const int f = f0 + ty, w = w0 + tx;
#pragma unroll
  for (int o = 0; o < 16; ++o)
    out[(((size_t)(b * 16 + o) << 10) + f) * 1024 + w] = acc[o];
}

// ------------------------------------------------------------------- launcher
extern "C" void kernel_launch(void* const* d_in, const int* in_sizes, int n_in,
                              void* d_out, int out_size, void* d_ws,
                              size_t ws_size, hipStream_t stream) {
  const float* x       = (const float*)d_in[0];
  const float* prev_qk = (const float*)d_in[1];
  const float* mask    = (const float*)d_in[2];
  const float* wq_conv = (const float*)d_in[3];
  const float* bq_conv = (const float*)d_in[4];
  const float* wq_pw   = (const float*)d_in[5];
  const float* wk_conv = (const float*)d_in[6];
  const float* bk_conv = (const float*)d_in[7];
  const float* wk_pw   = (const float*)d_in[8];
  const float* wv_conv = (const float*)d_in[9];
  const float* bv_conv = (const float*)d_in[10];
  const float* wv_pw   = (const float*)d_in[11];
  const float* wo_pw   = (const float*)d_in[12];
  const float* wo_dw   = (const float*)d_in[13];
  const float* wo_conv = (const float*)d_in[14];
  const float* bo_conv = (const float*)d_in[15];

  float* out = (float*)d_out;               // (B,C,F,W) = 33,554,432 fp32
  float* qk  = out + 32 * EL;               // (B,AM,H,W,W) = 67,108,864 fp32

  u16* ws16 = (u16*)d_ws;
  u16* wpwQ = ws16;                         //  4*EL bf16 each
  u16* wpwK = ws16 + 4 * EL;
  u16* wpwV = ws16 + 8 * EL;
  u16* wpwO = ws16 + 12 * EL;
  u16* yTq  = ws16 + 16 * EL;               //  8*EL bf16 each
  u16* yTk  = yTq + 8 * EL;
  u16* yTv  = yTk + 8 * EL;
  u16* Qt   = yTv + 8 * EL;
  u16* Kt   = Qt + 8 * EL;
  u16* Vn   = Kt + 8 * EL;
  u16* AT   = Vn + 8 * EL;
  u16* a2T  = AT + 8 * EL;
  u16* a3   = a2T + 8 * EL;

  cast_wpw<<<65536, 256, 0, stream>>>(wq_pw, wk_pw, wv_pw, wo_pw, ws16);
  conv_qkv<<<dim3(64, 64, 2), 256, 0, stream>>>(
      x, wq_conv, bq_conv, wk_conv, bk_conv, wv_conv, bv_conv, yTq, yTk, yTv);
  gemm_pw<1><<<dim3(8, 8, 8), 256, 0, stream>>>(wpwQ, yTq, Qt);
  gemm_pw<1><<<dim3(8, 8, 8), 256, 0, stream>>>(wpwK, yTk, Kt);
  gemm_pw<0><<<dim3(8, 8, 8), 256, 0, stream>>>(wpwV, yTv, Vn);
  attn_fused<<<dim3(8, 64), 256, 0, stream>>>(Qt, Kt, Vn, prev_qk, mask, qk,
                                              AT);
  mix_dw<<<2048, 256, 0, stream>>>(AT, wo_dw, a2T);
  gemm_pw<0><<<dim3(8, 8, 8), 256, 0, stream>>>(wpwO, a2T, a3);
  conv_out<<<dim3(64, 64, 2), 256, 0, stream>>>(x, a3, wo_conv, bo_conv, out);
}

// Round 2
// 1331.818 us; speedup vs baseline: 1.2160x; 1.0394x over previous
//
#include <hip/hip_runtime.h>

// ---------------------------------------------------------------------------
// MultichannelMultiheadAttention2: full decomposition
//   B=2 C=16 AM=4 HEADS=8 F=1024 W=1024 HD=128
// Pipeline:
//  1) cast_wpw: wq/wk/wv/wo_pw fp32 -> bf16 (float4 vectorized)
//  2) conv_qkv: 3x3 conv (x -> yq,yk,yv), written TRANSPOSED [b][am][w][f] bf16
//     (stage-all-16-channels LDS, 1 barrier per block)
//  3) gemm_pw<1> (q,k): C[f,w] = wpw[f,h]*y[h,w], epilogue fuses rotary and
//     stores per-head transposed Qt/Kt[b][am][head][qpos][d] bf16
//     gemm_pw<0> (v): natural store Vnat[b][am][f][w] bf16
//  4) attn_fused: flash-style fused S = QK^T/32 + prev + mask (fp32 -> qk out,
//     coalesced float4 via LDS bounce), online softmax, PV accumulate;
//     stores AT[b][am][qpos][head*128+d] bf16.
//  5) mix_dw: 4x4 channel mix -> a2T[b][o][w][h] bf16
//  6) gemm_pw<0> (o): wo_pw * a2 -> a3[b][am][f][w] bf16
//  7) conv_out: 3x3 conv over concat(x, a3) -> d_out(out) fp32
//     (stage-all-20-channels LDS, 1 barrier per block)
// ---------------------------------------------------------------------------

typedef unsigned short u16;
typedef __attribute__((ext_vector_type(8))) short bf16x8;
typedef __attribute__((ext_vector_type(4))) float f32x4;

constexpr size_t EL = 1024ull * 1024ull;  // one 1024x1024 plane

__device__ __forceinline__ u16 f2bf(float f) {
  union { float f; unsigned u; } v; v.f = f;
  return (u16)((v.u + 0x7fffu + ((v.u >> 16) & 1u)) >> 16);
}
__device__ __forceinline__ float bf2f(u16 h) {
  union { unsigned u; float f; } v; v.u = ((unsigned)h) << 16;
  return v.f;
}

// ---------------------------------------------------------------- cast weights
__global__ __launch_bounds__(256) void cast_wpw(const float* __restrict__ q,
                                                const float* __restrict__ k,
                                                const float* __restrict__ v,
                                                const float* __restrict__ o,
                                                u16* __restrict__ dst) {
  size_t i = ((size_t)blockIdx.x * 256 + threadIdx.x) * 4;  // 16,777,216 total
  int mat = (int)(i >> 22);
  size_t off = i & 4194303ull;
  const float* s = (mat == 0) ? q : (mat == 1) ? k : (mat == 2) ? v : o;
  float4 f = *(const float4*)(s + off);
  ushort4 r;
  r.x = f2bf(f.x); r.y = f2bf(f.y); r.z = f2bf(f.z); r.w = f2bf(f.w);
  *(ushort4*)(dst + i) = r;
}

// ------------------------------------------------------------------- conv qkv
// yT*[b][am][w][f]  (transposed so the pw GEMM's B^T operand is K-contiguous)
// Stage all 16 input channels (16 x 18x18 fp32 = 20.7 KB), single barrier.
__global__ __launch_bounds__(256) void conv_qkv(
    const float* __restrict__ x, const float* __restrict__ wq,
    const float* __restrict__ bq, const float* __restrict__ wk,
    const float* __restrict__ bk, const float* __restrict__ wv,
    const float* __restrict__ bv, u16* __restrict__ yTq,
    u16* __restrict__ yTk, u16* __restrict__ yTv) {
  __shared__ float xt[16 * 324];
  const int b = blockIdx.z;
  const int f0 = blockIdx.y * 16, w0 = blockIdx.x * 16;
  const int tx = threadIdx.x & 15;   // f-local
  const int ty = threadIdx.x >> 4;   // w-local

  // ---- stage: 16 channels x 324 halo elements, LDS addr == idx
  const float* xb = x + ((size_t)(b * 16) << 20);
  for (int idx = threadIdx.x; idx < 16 * 324; idx += 256) {
    const int r = idx / 18;            // 0..287  (c*18 + halo-row)
    const int cc = idx - r * 18;       // halo-col
    const int c = r / 18;
    const int rr = r - c * 18;         // halo-row
    const int gf = f0 - 1 + rr, gw = w0 - 1 + cc;
    float val = 0.f;
    if ((unsigned)gf < 1024u && (unsigned)gw < 1024u)
      val = xb[((size_t)c << 20) + ((size_t)gf << 10) + gw];
    xt[idx] = val;
  }
  __syncthreads();

  float acc[12];
#pragma unroll
  for (int p = 0; p < 12; ++p) acc[p] = 0.f;
  for (int c = 0; c < 16; ++c) {
    const float* xp = xt + c * 324;
    float xv[9];
#pragma unroll
    for (int ky = 0; ky < 3; ++ky)
#pragma unroll
      for (int kx = 0; kx < 3; ++kx)
        xv[ky * 3 + kx] = xp[(tx + ky) * 18 + (ty + kx)];
#pragma unroll
    for (int m = 0; m < 4; ++m) {
      const float* wqc = wq + (m * 16 + c) * 9;
      const float* wkc = wk + (m * 16 + c) * 9;
      const float* wvc = wv + (m * 16 + c) * 9;
#pragma unroll
      for (int t = 0; t < 9; ++t) {
        acc[m]     += xv[t] * wqc[t];
        acc[4 + m] += xv[t] * wkc[t];
        acc[8 + m] += xv[t] * wvc[t];
      }
    }
  }
  const int w = w0 + ty, f = f0 + tx;
#pragma unroll
  for (int m = 0; m < 4; ++m) {
    size_t o = ((((size_t)(b * 4 + m) << 10) + w) << 10) + f;
    yTq[o] = f2bf(acc[m] + bq[m]);
    yTk[o] = f2bf(acc[4 + m] + bk[m]);
    yTv[o] = f2bf(acc[8 + m] + bv[m]);
  }
}

// --------------------------------------------------------------- pw GEMM core
// C[f,w] = sum_h A[f,h] * Bt[w,h]; M=N=K=1024, lda=ldb=1024
// MODE 0: natural bf16 store C[z][f][w]
// MODE 1: rotary + per-head transposed store Qt[z][head][qpos][d]
template <int MODE>
__global__ __launch_bounds__(256) void gemm_pw(const u16* __restrict__ Aall,
                                               const u16* __restrict__ Ball,
                                               u16* __restrict__ Call) {
  const int z = blockIdx.z;         // b*4+am
  const int am = z & 3;
  const u16* __restrict__ A = Aall + (size_t)am * EL;   // weights per am
  const u16* __restrict__ Bt = Ball + (size_t)z * EL;
  const int bm = blockIdx.y * 128;
  const int bn = blockIdx.x * 128;
  __shared__ u16 As[128 * 40];      // padded stride 40 (bank spread)
  __shared__ u16 Bs[128 * 40];
  const int tid = threadIdx.x;
  const int lane = tid & 63, wv = tid >> 6;
  const int wm = (wv >> 1) * 64, wn = (wv & 1) * 64;
  const int mrow = lane & 15, quad = lane >> 4;
  const f32x4 fz = {0.f, 0.f, 0.f, 0.f};
  f32x4 acc[4][4];
#pragma unroll
  for (int i = 0; i < 4; ++i)
#pragma unroll
    for (int j = 0; j < 4; ++j) acc[i][j] = fz;

  for (int k0 = 0; k0 < 1024; k0 += 32) {
#pragma unroll
    for (int i = 0; i < 2; ++i) {
      const int cc = tid + i * 256;         // 0..511
      const int row = cc >> 2;              // 0..127
      const int kb = (cc & 3) * 8;          // bf16 elems within 32-wide row
      *(uint4*)(As + row * 40 + kb) =
          *(const uint4*)(A + (size_t)(bm + row) * 1024 + (k0 + kb));
      *(uint4*)(Bs + row * 40 + kb) =
          *(const uint4*)(Bt + (size_t)(bn + row) * 1024 + (k0 + kb));
    }
    __syncthreads();
    bf16x8 af[4], bfv[4];
#pragma unroll
    for (int t = 0; t < 4; ++t) {
      af[t]  = *(const bf16x8*)(As + (wm + 16 * t + mrow) * 40 + quad * 8);
      bfv[t] = *(const bf16x8*)(Bs + (wn + 16 * t + mrow) * 40 + quad * 8);
    }
#pragma unroll
    for (int mt = 0; mt < 4; ++mt)
#pragma unroll
      for (int nt = 0; nt < 4; ++nt)
        acc[mt][nt] = __builtin_amdgcn_mfma_f32_16x16x32_bf16(
            af[mt], bfv[nt], acc[mt][nt], 0, 0, 0);
    __syncthreads();
  }

  if (MODE == 0) {
    u16* C = Call + (size_t)z * EL;
#pragma unroll
    for (int mt = 0; mt < 4; ++mt) {
      const int rowb = bm + wm + 16 * mt + quad * 4;
#pragma unroll
      for (int nt = 0; nt < 4; ++nt) {
        const int col = bn + wn + 16 * nt + mrow;
#pragma unroll
        for (int r = 0; r < 4; ++r)
          C[(size_t)(rowb + r) * 1024 + col] = f2bf(acc[mt][nt][r]);
      }
    }
  } else {
    // rotary (lucidrains interleaved) + transposed per-head store
    u16* C = Call + (size_t)z * EL;   // [head][qpos][128]
    const int head = blockIdx.y;      // 128 rows == one head
#pragma unroll
    for (int mt = 0; mt < 4; ++mt) {
      const int d0 = wm + 16 * mt + quad * 4;  // within-head dim, even
      const float i1 = (float)(d0 >> 1);
      const float inv1 = __powf(10000.f, -i1 * (1.f / 64.f));
      const float inv2 = __powf(10000.f, -(i1 + 1.f) * (1.f / 64.f));
#pragma unroll
      for (int nt = 0; nt < 4; ++nt) {
        const int w = bn + wn + 16 * nt + mrow;  // qpos
        float s1, c1, s2, c2;
        __sincosf((float)w * inv1, &s1, &c1);
        __sincosf((float)w * inv2, &s2, &c2);
        const float x0 = acc[mt][nt][0], x1 = acc[mt][nt][1];
        const float x2 = acc[mt][nt][2], x3 = acc[mt][nt][3];
        ushort4 o4;
        o4.x = f2bf(x0 * c1 - x1 * s1);
        o4.y = f2bf(x1 * c1 + x0 * s1);
        o4.z = f2bf(x2 * c2 - x3 * s2);
        o4.w = f2bf(x3 * c2 + x2 * s2);
        *(ushort4*)(C + ((size_t)head * 1024 + w) * 128 + d0) = o4;
      }
    }
  }
}

// ------------------------------------------------------- fused flash attention
// One block per (z = bam*8+head, 128-row q block). 4 waves, wave w owns q rows
// [32w, 32w+32). Loop over 16 k-tiles of 64:
//   stage K/V tile -> S via MFMA -> scatter S to LDS (Sx, overlays dead K) ->
//   Phase B (coalesced): float4 prev/mask loads + fp32 S store (qk output),
//   online row max/sum, P=exp(S-m) bf16 into Ps, sf into sfl ->
//   rescale O by sf -> PV MFMA accumulate.
// Final: O /= l, store AT.
__global__ __launch_bounds__(256, 2) void attn_fused(
    const u16* __restrict__ Qt, const u16* __restrict__ Kt,
    const u16* __restrict__ Vn, const float* __restrict__ prev,
    const float* __restrict__ maskp, float* __restrict__ Sout,
    u16* __restrict__ AT) {
  const int z = blockIdx.y;
  const int bam = z >> 3, head = z & 7;
  const int bm = blockIdx.x * 128;
  const u16* __restrict__ Q = Qt + (size_t)z * (EL / 8);   // [1024 q][128 d]
  const u16* __restrict__ K = Kt + (size_t)z * (EL / 8);   // [1024 k][128 d]
  const u16* __restrict__ V =
      Vn + (size_t)bam * EL + (size_t)head * 128 * 1024;   // [128 d][1024 k]
  const float* __restrict__ Pz = prev + (size_t)z * EL;
  float* __restrict__ Sg = Sout + (size_t)z * EL;

  // LDS: Vs 18432 | Ps 18432 | sfl 512 | Sx(34816) union Ks(17408) = 72192 B
  __shared__ __align__(16) char smem[72192];
  u16* Vs = (u16*)smem;                  // [128 d][72]
  u16* Ps = (u16*)(smem + 18432);        // [128 q][72]
  float* sfl = (float*)(smem + 36864);   // [128]
  float* Sx = (float*)(smem + 37376);    // [128 q][68] fp32
  u16* Ks = (u16*)(smem + 37376);        // [64 k][136]  (overlay)

  const int tid = threadIdx.x;
  const int lane = tid & 63, wv = tid >> 6;
  const int mrow = lane & 15, quad = lane >> 4;
  const int wrow = wv * 32;              // wave's q-row base (tile-local)
  const int prow = lane >> 4;            // Phase-B row-within-group 0..3
  const int pcol4 = (lane & 15) * 4;     // Phase-B col base 0..60

  // Q fragments held in registers for the whole kernel
  bf16x8 qf[2][4];
#pragma unroll
  for (int mt = 0; mt < 2; ++mt)
#pragma unroll
    for (int kk = 0; kk < 4; ++kk)
      qf[mt][kk] = *(const bf16x8*)(
          Q + (size_t)(bm + wrow + 16 * mt + mrow) * 128 + kk * 32 + quad * 8);

  const f32x4 fz = {0.f, 0.f, 0.f, 0.f};
  f32x4 oacc[2][8];
#pragma unroll
  for (int mt = 0; mt < 2; ++mt)
#pragma unroll
    for (int nt = 0; nt < 8; ++nt) oacc[mt][nt] = fz;
  float m_st[8], l_st[8];
#pragma unroll
  for (int c = 0; c < 8; ++c) { m_st[c] = -3.0e38f; l_st[c] = 0.f; }

  for (int t = 0; t < 16; ++t) {
    const int kb = t * 64;
    // ---- stage K tile [64 k][128 d] and V tile [128 d][64 k]
#pragma unroll
    for (int i = 0; i < 4; ++i) {
      const int c = tid + i * 256;            // 0..1023
      const int row = c >> 4, c8 = (c & 15) * 8;
      *(uint4*)(Ks + row * 136 + c8) =
          *(const uint4*)(K + (size_t)(kb + row) * 128 + c8);
    }
#pragma unroll
    for (int i = 0; i < 4; ++i) {
      const int c = tid + i * 256;
      const int row = c >> 3, c8 = (c & 7) * 8;
      *(uint4*)(Vs + row * 72 + c8) =
          *(const uint4*)(V + (size_t)row * 1024 + kb + c8);
    }
    __syncthreads();

    // ---- S = Q K^T (raw, unscaled)
    f32x4 sacc[2][4];
#pragma unroll
    for (int mt = 0; mt < 2; ++mt)
#pragma unroll
      for (int nt = 0; nt < 4; ++nt) sacc[mt][nt] = fz;
#pragma unroll
    for (int kk = 0; kk < 4; ++kk) {
      bf16x8 bk[4];
#pragma unroll
      for (int nt = 0; nt < 4; ++nt)
        bk[nt] = *(const bf16x8*)(Ks + (16 * nt + mrow) * 136 + kk * 32 +
                                  quad * 8);
#pragma unroll
      for (int mt = 0; mt < 2; ++mt)
#pragma unroll
        for (int nt = 0; nt < 4; ++nt)
          sacc[mt][nt] = __builtin_amdgcn_mfma_f32_16x16x32_bf16(
              qf[mt][kk], bk[nt], sacc[mt][nt], 0, 0, 0);
    }
    __syncthreads();   // all waves done reading Ks (Sx overlays it)

    // ---- scatter S into Sx (wave-local rows; 2-way banks = free)
#pragma unroll
    for (int mt = 0; mt < 2; ++mt)
#pragma unroll
      for (int nt = 0; nt < 4; ++nt)
#pragma unroll
        for (int r = 0; r < 4; ++r)
          Sx[(wrow + 16 * mt + quad * 4 + r) * 68 + 16 * nt + mrow] =
              sacc[mt][nt][r];

    // ---- Phase B: coalesced epilogue + online softmax (wave-local rows)
#pragma unroll
    for (int c = 0; c < 8; ++c) {
      const int rloc = wrow + c * 4 + prow;                   // 0..127
      const size_t gidx = (size_t)(bm + rloc) * 1024 + kb + pcol4;
      f32x4 sx = *(const f32x4*)(Sx + rloc * 68 + pcol4);
      f32x4 pv = __builtin_nontemporal_load((const f32x4*)(Pz + gidx));
      f32x4 mv = *(const f32x4*)(maskp + gidx);
      f32x4 s;
      s.x = sx.x * 0.03125f + pv.x + mv.x;
      s.y = sx.y * 0.03125f + pv.y + mv.y;
      s.z = sx.z * 0.03125f + pv.z + mv.z;
      s.w = sx.w * 0.03125f + pv.w + mv.w;
      __builtin_nontemporal_store(s, (f32x4*)(Sg + gidx));
      float mx = fmaxf(fmaxf(s.x, s.y), fmaxf(s.z, s.w));
      mx = fmaxf(mx, __shfl_xor(mx, 1, 64));
      mx = fmaxf(mx, __shfl_xor(mx, 2, 64));
      mx = fmaxf(mx, __shfl_xor(mx, 4, 64));
      mx = fmaxf(mx, __shfl_xor(mx, 8, 64));
      const float mn = fmaxf(m_st[c], mx);
      const float sf = __expf(m_st[c] - mn);
      m_st[c] = mn;
      const float p0 = __expf(s.x - mn), p1 = __expf(s.y - mn);
      const float p2 = __expf(s.z - mn), p3 = __expf(s.w - mn);
      float rs = p0 + p1 + p2 + p3;
      rs += __shfl_xor(rs, 1, 64);
      rs += __shfl_xor(rs, 2, 64);
      rs += __shfl_xor(rs, 4, 64);
      rs += __shfl_xor(rs, 8, 64);
      l_st[c] = l_st[c] * sf + rs;
      uint2 pk;
      pk.x = (unsigned)f2bf(p0) | ((unsigned)f2bf(p1) << 16);
      pk.y = (unsigned)f2bf(p2) | ((unsigned)f2bf(p3) << 16);
      *(uint2*)(Ps + rloc * 72 + pcol4) = pk;
      if ((lane & 15) == 0) sfl[rloc] = sf;
    }

    // ---- rescale O by this tile's sf (rows wave-local; broadcast LDS reads)
#pragma unroll
    for (int mt = 0; mt < 2; ++mt)
#pragma unroll
      for (int r = 0; r < 4; ++r) {
        const float sfv = sfl[wrow + 16 * mt + quad * 4 + r];
#pragma unroll
        for (int nt = 0; nt < 8; ++nt) oacc[mt][nt][r] *= sfv;
      }

    // ---- PV: O += P * V
#pragma unroll
    for (int kk = 0; kk < 2; ++kk) {
      bf16x8 pa[2], bv[8];
#pragma unroll
      for (int mt = 0; mt < 2; ++mt)
        pa[mt] = *(const bf16x8*)(Ps + (wrow + 16 * mt + mrow) * 72 + kk * 32 +
                                  quad * 8);
#pragma unroll
      for (int nt = 0; nt < 8; ++nt)
        bv[nt] = *(const bf16x8*)(Vs + (16 * nt + mrow) * 72 + kk * 32 +
                                  quad * 8);
#pragma unroll
      for (int mt = 0; mt < 2; ++mt)
#pragma unroll
        for (int nt = 0; nt < 8; ++nt)
          oacc[mt][nt] = __builtin_amdgcn_mfma_f32_16x16x32_bf16(
              pa[mt], bv[nt], oacc[mt][nt], 0, 0, 0);
    }
    __syncthreads();   // Vs/Ks region free for next tile's staging
  }

  // ---- final normalize + store AT[bam][qpos][head*128 + d]
#pragma unroll
  for (int c = 0; c < 8; ++c)
    if ((lane & 15) == 0) sfl[wrow + c * 4 + prow] = 1.f / l_st[c];
  __syncthreads();
  u16* C = AT + (size_t)bam * EL + (size_t)head * 128;
#pragma unroll
  for (int mt = 0; mt < 2; ++mt)
#pragma unroll
    for (int r = 0; r < 4; ++r) {
      const int rloc = wrow + 16 * mt + quad * 4 + r;
      const float inv = sfl[rloc];
      const int grow = bm + rloc;
#pragma unroll
      for (int nt = 0; nt < 8; ++nt)
        C[(size_t)grow * 1024 + 16 * nt + mrow] =
            f2bf(oacc[mt][nt][r] * inv);
    }
}

// -------------------------------------------------------------- wo_dw 4x4 mix
__global__ __launch_bounds__(256) void mix_dw(const u16* __restrict__ AT,
                                              const float* __restrict__ dw,
                                              u16* __restrict__ a2T) {
  const size_t i = (size_t)blockIdx.x * 256 + threadIdx.x;  // 524288 total
  const int b = (int)(i >> 18);
  const size_t pos = (i & 262143ull) << 2;  // 4 consecutive f
  const u16* bb = AT + (size_t)b * 4 * EL + pos;
  float4 v[4];
#pragma unroll
  for (int c = 0; c < 4; ++c) {
    ushort4 t = *(const ushort4*)(bb + (size_t)c * EL);
    v[c].x = bf2f(t.x); v[c].y = bf2f(t.y); v[c].z = bf2f(t.z); v[c].w = bf2f(t.w);
  }
#pragma unroll
  for (int o = 0; o < 4; ++o) {
    const float w0 = dw[o * 4 + 0], w1 = dw[o * 4 + 1];
    const float w2 = dw[o * 4 + 2], w3 = dw[o * 4 + 3];
    ushort4 s;
    s.x = f2bf(w0 * v[0].x + w1 * v[1].x + w2 * v[2].x + w3 * v[3].x);
    s.y = f2bf(w0 * v[0].y + w1 * v[1].y + w2 * v[2].y + w3 * v[3].y);
    s.z = f2bf(w0 * v[0].z + w1 * v[1].z + w2 * v[2].z + w3 * v[3].z);
    s.w = f2bf(w0 * v[0].w + w1 * v[1].w + w2 * v[2].w + w3 * v[3].w);
    *(ushort4*)(a2T + (size_t)b * 4 * EL + (size_t)o * EL + pos) = s;
  }
}

// ------------------------------------------------------------------ conv out
// Stage all 20 input channels (20 x 18x18 fp32 = 25.9 KB), single barrier.
__global__ __launch_bounds__(256) void conv_out(const float* __restrict__ x,
                                                const u16* __restrict__ a3,
                                                const float* __restrict__ wo,
                                                const float* __restrict__ bo,
                                                float* __restrict__ out) {
  __shared__ float xt[20 * 324];
  const int b = blockIdx.z;
  const int f0 = blockIdx.y * 16, w0 = blockIdx.x * 16;
  const int tx = threadIdx.x & 15;   // w-local
  const int ty = threadIdx.x >> 4;   // f-local

  // ---- stage: 20 channels x 324 halo elements, LDS addr == idx
  const float* xb = x + ((size_t)(b * 16) << 20);
  const u16* ab = a3 + ((size_t)(b * 4) << 20);
  for (int idx = threadIdx.x; idx < 20 * 324; idx += 256) {
    const int r = idx / 18;            // c*18 + halo-row
    const int cc = idx - r * 18;       // halo-col
    const int c = r / 18;
    const int rr = r - c * 18;         // halo-row
    const int gf = f0 - 1 + rr, gw = w0 - 1 + cc;
    float val = 0.f;
    if ((unsigned)gf < 1024u && (unsigned)gw < 1024u) {
      if (c < 16)
        val = xb[((size_t)c << 20) + ((size_t)gf << 10) + gw];
      else
        val = bf2f(ab[((size_t)(c - 16) << 20) + ((size_t)gf << 10) + gw]);
    }
    xt[idx] = val;
  }
  __syncthreads();

  float acc[16];
#pragma unroll
  for (int o = 0; o < 16; ++o) acc[o] = bo[o];
  for (int c = 0; c < 20; ++c) {
    const float* xp = xt + c * 324;
    float xv[9];
#pragma unroll
    for (int ky = 0; ky < 3; ++ky)
#pragma unroll
      for (int kx = 0; kx < 3; ++kx)
        xv[ky * 3 + kx] = xp[(ty + ky) * 18 + (tx + kx)];
#pragma unroll
    for (int o = 0; o < 16; ++o) {
      const float* wc = wo + (o * 20 + c) * 9;
#pragma unroll
      for (int t = 0; t < 9; ++t) acc[o] += xv[t] * wc[t];
    }
  }
  const int f = f0 + ty, w = w0 + tx;
#pragma unroll
  for (int o = 0; o < 16; ++o)
    out[(((size_t)(b * 16 + o) << 10) + f) * 1024 + w] = acc[o];
}

// ------------------------------------------------------------------- launcher
extern "C" void kernel_launch(void* const* d_in, const int* in_sizes, int n_in,
                              void* d_out, int out_size, void* d_ws,
                              size_t ws_size, hipStream_t stream) {
  const float* x       = (const float*)d_in[0];
  const float* prev_qk = (const float*)d_in[1];
  const float* mask    = (const float*)d_in[2];
  const float* wq_conv = (const float*)d_in[3];
  const float* bq_conv = (const float*)d_in[4];
  const float* wq_pw   = (const float*)d_in[5];
  const float* wk_conv = (const float*)d_in[6];
  const float* bk_conv = (const float*)d_in[7];
  const float* wk_pw   = (const float*)d_in[8];
  const float* wv_conv = (const float*)d_in[9];
  const float* bv_conv = (const float*)d_in[10];
  const float* wv_pw   = (const float*)d_in[11];
  const float* wo_pw   = (const float*)d_in[12];
  const float* wo_dw   = (const float*)d_in[13];
  const float* wo_conv = (const float*)d_in[14];
  const float* bo_conv = (const float*)d_in[15];

  float* out = (float*)d_out;               // (B,C,F,W) = 33,554,432 fp32
  float* qk  = out + 32 * EL;               // (B,AM,H,W,W) = 67,108,864 fp32

  u16* ws16 = (u16*)d_ws;
  u16* wpwQ = ws16;                         //  4*EL bf16 each
  u16* wpwK = ws16 + 4 * EL;
  u16* wpwV = ws16 + 8 * EL;
  u16* wpwO = ws16 + 12 * EL;
  u16* yTq  = ws16 + 16 * EL;               //  8*EL bf16 each
  u16* yTk  = yTq + 8 * EL;
  u16* yTv  = yTk + 8 * EL;
  u16* Qt   = yTv + 8 * EL;
  u16* Kt   = Qt + 8 * EL;
  u16* Vn   = Kt + 8 * EL;
  u16* AT   = Vn + 8 * EL;
  u16* a2T  = AT + 8 * EL;
  u16* a3   = a2T + 8 * EL;

  cast_wpw<<<16384, 256, 0, stream>>>(wq_pw, wk_pw, wv_pw, wo_pw, ws16);
  conv_qkv<<<dim3(64, 64, 2), 256, 0, stream>>>(
      x, wq_conv, bq_conv, wk_conv, bk_conv, wv_conv, bv_conv, yTq, yTk, yTv);
  gemm_pw<1><<<dim3(8, 8, 8), 256, 0, stream>>>(wpwQ, yTq, Qt);
  gemm_pw<1><<<dim3(8, 8, 8), 256, 0, stream>>>(wpwK, yTk, Kt);
  gemm_pw<0><<<dim3(8, 8, 8), 256, 0, stream>>>(wpwV, yTv, Vn);
  attn_fused<<<dim3(8, 64), 256, 0, stream>>>(Qt, Kt, Vn, prev_qk, mask, qk,
                                              AT);
  mix_dw<<<2048, 256, 0, stream>>>(AT, wo_dw, a2T);
  gemm_pw<0><<<dim3(8, 8, 8), 256, 0, stream>>>(wpwO, a2T, a3);
  conv_out<<<dim3(64, 64, 2), 256, 0, stream>>>(x, a3, wo_conv, bo_conv, out);
}